// Round 1
// baseline (83.645 us; speedup 1.0000x reference)
//
#include <hip/hip_runtime.h>
#include <hip/hip_bf16.h>

// B=8, N=64, P=128, DNODE=2048, DEDGE=1024, DEMB=512, E=32768
// Key insight: edge_locating_tensor is the canonical meshgrid -> lookup is
// b*4096 + i*64 + j. Only 2048 of 32768 edge embeddings are used; fold the
// (e1+e2)*0.5 average into the GEMM input (linear op).

typedef _Float16 h16;
typedef h16 h16x4 __attribute__((ext_vector_type(4)));
typedef h16 h16x8 __attribute__((ext_vector_type(8)));
typedef float f32x4 __attribute__((ext_vector_type(4)));

// ---------------- ws layout (bytes) ----------------
// x_h   : 0         512*2048*2  = 2097152
// W3t   : 2097152   1536*2048*2 = 6291456   (phi|psi|node, transposed, K-major)
// Wrelt : 8388608   512*1024*2  = 1048576
// G     : 9437184   1024*1024*2 = 2097152   (0.5*(f_fwd+f_rev) per pair, f16)
// b3    : 11534336  1536*4      = 6144
// Y     : 11540480  512*1536*4  = 3145728   (phi|psi|node_emb fp32)

// Transpose+convert weights to f16, K-major ("B^T" GEMM input).
__global__ void k_transpose(const float* __restrict__ Wphi, const float* __restrict__ Wpsi,
                            const float* __restrict__ Wnode, const float* __restrict__ Wrel,
                            h16* __restrict__ W3t, h16* __restrict__ Wrelt) {
  __shared__ float t[32][33];
  int bid = blockIdx.x;
  const float* src; h16* dst; int K, tk, tn;
  if (bid < 3072) {
    int mat = bid >> 10, rem = bid & 1023;
    tk = rem >> 4; tn = rem & 15;
    src = mat == 0 ? Wphi : (mat == 1 ? Wpsi : Wnode);
    K = 2048;
    dst = W3t + (long)mat * 512 * 2048;
  } else {
    int rem = bid - 3072;
    tk = rem >> 4; tn = rem & 15;
    src = Wrel; K = 1024; dst = Wrelt;
  }
  int tx = threadIdx.x & 31, ty = threadIdx.x >> 5;
#pragma unroll
  for (int it = 0; it < 4; ++it)
    t[ty + it*8][tx] = src[(long)(tk*32 + ty + it*8)*512 + tn*32 + tx];
  __syncthreads();
#pragma unroll
  for (int it = 0; it < 4; ++it)
    dst[(long)(tn*32 + ty + it*8)*K + tk*32 + tx] = (h16)t[tx][ty + it*8];
}

// Convert x -> f16 (blocks 0..511) and assemble concat bias b3 (blocks 512..517).
__global__ void k_cvt_x(const float* __restrict__ x,
                        const float* __restrict__ bphi, const float* __restrict__ bpsi,
                        const float* __restrict__ bnode,
                        h16* __restrict__ xh, float* __restrict__ b3) {
  int bid = blockIdx.x;
  if (bid < 512) {
    int idx = (bid*256 + threadIdx.x) * 8;
    const float4* xv = (const float4*)(x + idx);
    float4 v0 = xv[0], v1 = xv[1];
    h16x8 o;
    o[0]=(h16)v0.x; o[1]=(h16)v0.y; o[2]=(h16)v0.z; o[3]=(h16)v0.w;
    o[4]=(h16)v1.x; o[5]=(h16)v1.y; o[6]=(h16)v1.z; o[7]=(h16)v1.w;
    *(h16x8*)(xh + idx) = o;
  } else {
    int i = (bid - 512)*256 + threadIdx.x;
    if (i < 1536) b3[i] = i < 512 ? bphi[i] : (i < 1024 ? bpsi[i-512] : bnode[i-1024]);
  }
}

// Gather the two interaction_feature rows per pair, average, convert to f16.
__global__ void k_gather(const float* __restrict__ feat, const int* __restrict__ pairs,
                         h16* __restrict__ G) {
  int r = blockIdx.x;            // r = b*128 + p
  int b = r >> 7;
  int i0 = pairs[r*2], i1 = pairs[r*2+1];
  const float4* f0 = (const float4*)(feat + (long)((b*64 + i0)*64 + i1) * 1024);
  const float4* f1 = (const float4*)(feat + (long)((b*64 + i1)*64 + i0) * 1024);
  int k = threadIdx.x;           // 256 threads * 4 floats = 1024
  float4 a = f0[k], c = f1[k];
  h16x4 o;
  o[0]=(h16)(0.5f*(a.x+c.x)); o[1]=(h16)(0.5f*(a.y+c.y));
  o[2]=(h16)(0.5f*(a.z+c.z)); o[3]=(h16)(0.5f*(a.w+c.w));
  *(h16x4*)(G + (long)r*1024 + k*4) = o;
}

// C[cbase + row*ldc + col] = A(M x K, f16 row-major) @ Bt^T (Bt is N x K) + bias[col]
// 64x64 tile / block, 4 waves in 2x2, each wave 32x32 via 16x16x16 f16 MFMA.
__global__ __launch_bounds__(256) void k_gemm(const h16* __restrict__ A, const h16* __restrict__ Bt,
                       const float* __restrict__ bias, float* __restrict__ C,
                       int K, int ldc, long cbase) {
  __shared__ __align__(16) h16 As[64][36];
  __shared__ __align__(16) h16 Bs[64][36];
  int tid = threadIdx.x;
  int lane = tid & 63;
  int wave = tid >> 6;
  int wm = wave >> 1, wn = wave & 1;
  int tileM = blockIdx.y * 64, tileN = blockIdx.x * 64;
  int lrow = tid >> 2, lcol = (tid & 3) * 8;
  f32x4 acc[2][2] = {};
  const h16* Ag = A + (long)(tileM + lrow) * K + lcol;
  const h16* Bg = Bt + (long)(tileN + lrow) * K + lcol;
  for (int k0 = 0; k0 < K; k0 += 32) {
    h16x8 av = *(const h16x8*)(Ag + k0);
    h16x8 bv = *(const h16x8*)(Bg + k0);
    __syncthreads();
    h16x4 alo = {av[0],av[1],av[2],av[3]}, ahi = {av[4],av[5],av[6],av[7]};
    h16x4 blo = {bv[0],bv[1],bv[2],bv[3]}, bhi = {bv[4],bv[5],bv[6],bv[7]};
    *(h16x4*)&As[lrow][lcol]   = alo;
    *(h16x4*)&As[lrow][lcol+4] = ahi;
    *(h16x4*)&Bs[lrow][lcol]   = blo;
    *(h16x4*)&Bs[lrow][lcol+4] = bhi;
    __syncthreads();
#pragma unroll
    for (int ks = 0; ks < 2; ++ks) {
      int kb = ks*16 + 4*(lane >> 4);
      h16x4 a0 = *(const h16x4*)&As[wm*32 + (lane&15)][kb];
      h16x4 a1 = *(const h16x4*)&As[wm*32 + 16 + (lane&15)][kb];
      h16x4 b0 = *(const h16x4*)&Bs[wn*32 + (lane&15)][kb];
      h16x4 b1 = *(const h16x4*)&Bs[wn*32 + 16 + (lane&15)][kb];
      acc[0][0] = __builtin_amdgcn_mfma_f32_16x16x16f16(a0, b0, acc[0][0], 0,0,0);
      acc[0][1] = __builtin_amdgcn_mfma_f32_16x16x16f16(a0, b1, acc[0][1], 0,0,0);
      acc[1][0] = __builtin_amdgcn_mfma_f32_16x16x16f16(a1, b0, acc[1][0], 0,0,0);
      acc[1][1] = __builtin_amdgcn_mfma_f32_16x16x16f16(a1, b1, acc[1][1], 0,0,0);
    }
  }
  int r0 = 4*(lane >> 4), c0 = lane & 15;
#pragma unroll
  for (int m = 0; m < 2; ++m)
#pragma unroll
    for (int n = 0; n < 2; ++n) {
      int row = tileM + wm*32 + m*16 + r0;
      int col = tileN + wn*32 + n*16 + c0;
      float bb = bias[col];
#pragma unroll
      for (int r = 0; r < 4; ++r)
        C[cbase + (long)(row + r)*ldc + col] = acc[m][n][r] + bb;
    }
}

// relatedness_score[b,i,j] = sigmoid(phi[b,i,:] . psi[b,j,:]), fp32.
__global__ void k_scores(const float* __restrict__ Y, float* __restrict__ out) {
  __shared__ float ph[512];
  int bi = blockIdx.x;           // b*64 + i
  int b = bi >> 6;
  const float* phi = Y + (long)bi * 1536;
  ph[threadIdx.x] = phi[threadIdx.x];
  ph[threadIdx.x + 256] = phi[threadIdx.x + 256];
  __syncthreads();
  int j = threadIdx.x >> 2, q = threadIdx.x & 3;
  const float* psi = Y + (long)(b*64 + j) * 1536 + 512;
  float s = 0.f;
#pragma unroll 4
  for (int k = q*128; k < q*128 + 128; ++k) s += ph[k] * psi[k];
  s += __shfl_xor(s, 1);
  s += __shfl_xor(s, 2);
  if (q == 0) out[(long)bi*64 + j] = 1.f / (1.f + expf(-s));
}

// classifier first half: 0.5*(node_emb[b,i0]+node_emb[b,i1])
__global__ void k_first(const float* __restrict__ Y, const int* __restrict__ pairs,
                        float* __restrict__ out) {
  int r = blockIdx.x;
  int b = r >> 7;
  int i0 = pairs[r*2], i1 = pairs[r*2+1];
  const float* n0 = Y + (long)(b*64 + i0)*1536 + 1024;
  const float* n1 = Y + (long)(b*64 + i1)*1536 + 1024;
  float* o = out + 32768 + (long)r*1024;
  for (int c = threadIdx.x; c < 512; c += 256)
    o[c] = 0.5f*(n0[c] + n1[c]);
}

extern "C" void kernel_launch(void* const* d_in, const int* in_sizes, int n_in,
                              void* d_out, int out_size, void* d_ws, size_t ws_size,
                              hipStream_t stream) {
  const float* x     = (const float*)d_in[0];
  const float* feat  = (const float*)d_in[1];
  const float* Wphi  = (const float*)d_in[2];
  const float* bphi  = (const float*)d_in[3];
  const float* Wpsi  = (const float*)d_in[4];
  const float* bpsi  = (const float*)d_in[5];
  const float* Wnode = (const float*)d_in[6];
  const float* bnode = (const float*)d_in[7];
  const float* Wrel  = (const float*)d_in[8];
  const float* brel  = (const float*)d_in[9];
  const int*   pairs = (const int*)d_in[10];
  float* out = (float*)d_out;
  char* ws = (char*)d_ws;

  h16*   xh    = (h16*)(ws + 0);
  h16*   W3t   = (h16*)(ws + 2097152);
  h16*   Wrelt = (h16*)(ws + 8388608);
  h16*   G     = (h16*)(ws + 9437184);
  float* b3    = (float*)(ws + 11534336);
  float* Y     = (float*)(ws + 11540480);

  k_transpose<<<dim3(3584), dim3(256), 0, stream>>>(Wphi, Wpsi, Wnode, Wrel, W3t, Wrelt);
  k_cvt_x   <<<dim3(518),  dim3(256), 0, stream>>>(x, bphi, bpsi, bnode, xh, b3);
  k_gather  <<<dim3(1024), dim3(256), 0, stream>>>(feat, pairs, G);
  // Y(512x1536) = xh(512x2048) @ W3t^T + b3
  k_gemm<<<dim3(24, 8),  dim3(256), 0, stream>>>(xh, W3t, b3, Y, 2048, 1536, 0L);
  // classifier second half: G(1024x1024) @ Wrelt^T + brel -> out[32768 + r*1024 + 512 + c]
  k_gemm<<<dim3(8, 16),  dim3(256), 0, stream>>>(G, Wrelt, brel, out, 1024, 1024, (long)(32768 + 512));
  k_scores<<<dim3(512),  dim3(256), 0, stream>>>(Y, out);
  k_first <<<dim3(1024), dim3(256), 0, stream>>>(Y, pairs, out);
}

// Round 2
// 52.174 us; speedup vs baseline: 1.6032x; 1.6032x over previous
//
#include <hip/hip_runtime.h>
#include <hip/hip_bf16.h>

// B=8, N=64, P=128, DNODE=2048, DEDGE=1024, DEMB=512, E=32768
// edge_locating_tensor is the canonical meshgrid -> lookup(b,i,j) = b*4096+i*64+j.
// Only 2*B*P=2048 of 32768 edge rows are used; (e1+e2)*0.5 folds into the GEMM
// input (linearity), so the edge GEMM is 1024x512x1024 instead of 32768x512x1024.
// 3 launches: prep (transpose||cvt||gather), gemm (both GEMMs), epilogue (scores||first).

typedef _Float16 h16;
typedef h16 h16x4 __attribute__((ext_vector_type(4)));
typedef h16 h16x8 __attribute__((ext_vector_type(8)));
typedef float f32x4 __attribute__((ext_vector_type(4)));

// ---------------- ws layout (bytes) ----------------
// xh    : 0         512*2048*2  = 2097152
// W3t   : 2097152   1536*2048*2 = 6291456   (phi|psi|node, K-major)
// Wrelt : 8388608   512*1024*2  = 1048576
// G     : 9437184   1024*1024*2 = 2097152   (0.5*(f_fwd+f_rev), f16)
// b3    : 11534336  1536*4      = 6144
// Y     : 11540480  512*1536*4  = 3145728   (phi|psi|node_emb fp32)

__global__ __launch_bounds__(256) void k_prep(
    const float* __restrict__ Wphi, const float* __restrict__ Wpsi,
    const float* __restrict__ Wnode, const float* __restrict__ Wrel,
    const float* __restrict__ x, const float* __restrict__ bphi,
    const float* __restrict__ bpsi, const float* __restrict__ bnode,
    const float* __restrict__ feat, const int* __restrict__ pairs,
    h16* __restrict__ W3t, h16* __restrict__ Wrelt, h16* __restrict__ xh,
    float* __restrict__ b3, h16* __restrict__ G) {
  __shared__ float t[32][33];
  int bid = blockIdx.x;
  if (bid < 3584) {
    // ---- weight transpose+cvt: [K][512] f32 -> [512][K] f16 ----
    const float* src; h16* dst; int K, tk, tn;
    if (bid < 3072) {
      int mat = bid >> 10, rem = bid & 1023;
      tk = rem >> 4; tn = rem & 15;
      src = mat == 0 ? Wphi : (mat == 1 ? Wpsi : Wnode);
      K = 2048; dst = W3t + (long)mat * 512 * 2048;
    } else {
      int rem = bid - 3072;
      tk = rem >> 4; tn = rem & 15;
      src = Wrel; K = 1024; dst = Wrelt;
    }
    int tx = threadIdx.x & 31, ty = threadIdx.x >> 5;
#pragma unroll
    for (int it = 0; it < 4; ++it)
      t[ty + it*8][tx] = src[(long)(tk*32 + ty + it*8)*512 + tn*32 + tx];
    __syncthreads();
#pragma unroll
    for (int it = 0; it < 4; ++it)
      dst[(long)(tn*32 + ty + it*8)*K + tk*32 + tx] = (h16)t[tx][ty + it*8];
  } else if (bid < 4102) {
    int b2 = bid - 3584;
    if (b2 < 512) {
      // ---- x f32 -> f16 ----
      int idx = (b2*256 + threadIdx.x) * 8;
      const float4* xv = (const float4*)(x + idx);
      float4 v0 = xv[0], v1 = xv[1];
      h16x8 o;
      o[0]=(h16)v0.x; o[1]=(h16)v0.y; o[2]=(h16)v0.z; o[3]=(h16)v0.w;
      o[4]=(h16)v1.x; o[5]=(h16)v1.y; o[6]=(h16)v1.z; o[7]=(h16)v1.w;
      *(h16x8*)(xh + idx) = o;
    } else {
      int i = (b2 - 512)*256 + threadIdx.x;
      if (i < 1536) b3[i] = i < 512 ? bphi[i] : (i < 1024 ? bpsi[i-512] : bnode[i-1024]);
    }
  } else {
    // ---- gather fwd+rev edge features, average, cvt f16 ----
    int r = bid - 4102;            // r = b*128 + p
    int b = r >> 7;
    int i0 = pairs[r*2], i1 = pairs[r*2+1];
    const float4* f0 = (const float4*)(feat + (long)((b*64 + i0)*64 + i1) * 1024);
    const float4* f1 = (const float4*)(feat + (long)((b*64 + i1)*64 + i0) * 1024);
    int k = threadIdx.x;
    float4 a = f0[k], c = f1[k];
    h16x4 o;
    o[0]=(h16)(0.5f*(a.x+c.x)); o[1]=(h16)(0.5f*(a.y+c.y));
    o[2]=(h16)(0.5f*(a.z+c.z)); o[3]=(h16)(0.5f*(a.w+c.w));
    *(h16x4*)(G + (long)r*1024 + k*4) = o;
  }
}

// Both GEMMs in one launch. 64x64 tile, 4 waves (2x2), each wave 32x32 out,
// BK=64, mfma_f32_16x16x32_f16, b128 LDS fragment reads, +8 h16 row pad.
__global__ __launch_bounds__(256) void k_gemm(
    const h16* __restrict__ A1, const h16* __restrict__ B1,
    const float* __restrict__ bias1, float* __restrict__ C1,
    const h16* __restrict__ A2, const h16* __restrict__ B2,
    const float* __restrict__ bias2, float* __restrict__ C2) {
  __shared__ __align__(16) h16 As[64][72];
  __shared__ __align__(16) h16 Bs[64][72];
  int bid = blockIdx.x;
  const h16 *A, *Bt; const float* bias; float* C;
  int K, ldc, tileM, tileN;
  if (bid < 192) {               // Y(512x1536) = xh @ W3t^T + b3
    A = A1; Bt = B1; bias = bias1; C = C1; K = 2048; ldc = 1536;
    tileM = (bid / 24) * 64; tileN = (bid % 24) * 64;
  } else {                       // edge(1024x512) = G @ Wrelt^T + brel
    int r = bid - 192;
    A = A2; Bt = B2; bias = bias2; C = C2; K = 1024; ldc = 1024;
    tileM = (r / 8) * 64; tileN = (r % 8) * 64;
  }
  int tid = threadIdx.x, lane = tid & 63, wave = tid >> 6;
  int wm = wave >> 1, wn = wave & 1;
  int srow = tid >> 2, skp = (tid & 3) * 16;
  const h16* Ag = A + (long)(tileM + srow) * K + skp;
  const h16* Bg = Bt + (long)(tileN + srow) * K + skp;
  f32x4 acc[2][2] = {};
  int fr = lane & 15, kg = (lane >> 4) * 8;
  for (int k0 = 0; k0 < K; k0 += 64) {
    h16x8 a0 = *(const h16x8*)(Ag + k0);
    h16x8 a1 = *(const h16x8*)(Ag + k0 + 8);
    h16x8 b0 = *(const h16x8*)(Bg + k0);
    h16x8 b1 = *(const h16x8*)(Bg + k0 + 8);
    __syncthreads();
    *(h16x8*)&As[srow][skp]     = a0;
    *(h16x8*)&As[srow][skp + 8] = a1;
    *(h16x8*)&Bs[srow][skp]     = b0;
    *(h16x8*)&Bs[srow][skp + 8] = b1;
    __syncthreads();
#pragma unroll
    for (int kc = 0; kc < 2; ++kc) {
      int kb = kc * 32 + kg;
      h16x8 fa0 = *(const h16x8*)&As[wm*32 + fr][kb];
      h16x8 fa1 = *(const h16x8*)&As[wm*32 + 16 + fr][kb];
      h16x8 fb0 = *(const h16x8*)&Bs[wn*32 + fr][kb];
      h16x8 fb1 = *(const h16x8*)&Bs[wn*32 + 16 + fr][kb];
      acc[0][0] = __builtin_amdgcn_mfma_f32_16x16x32_f16(fa0, fb0, acc[0][0], 0,0,0);
      acc[0][1] = __builtin_amdgcn_mfma_f32_16x16x32_f16(fa0, fb1, acc[0][1], 0,0,0);
      acc[1][0] = __builtin_amdgcn_mfma_f32_16x16x32_f16(fa1, fb0, acc[1][0], 0,0,0);
      acc[1][1] = __builtin_amdgcn_mfma_f32_16x16x32_f16(fa1, fb1, acc[1][1], 0,0,0);
    }
  }
  int r0 = 4 * (lane >> 4), c0 = lane & 15;
#pragma unroll
  for (int m = 0; m < 2; ++m)
#pragma unroll
    for (int n = 0; n < 2; ++n) {
      int row = tileM + wm*32 + m*16 + r0;
      int col = tileN + wn*32 + n*16 + c0;
      float bb = bias[col];
#pragma unroll
      for (int r = 0; r < 4; ++r)
        C[(long)(row + r) * ldc + col] = acc[m][n][r] + bb;
    }
}

// scores (blocks 0..511) || classifier first half (blocks 512..1535)
__global__ __launch_bounds__(256) void k_epilogue(
    const float* __restrict__ Y, const int* __restrict__ pairs,
    float* __restrict__ out) {
  __shared__ float ph[512];
  int bid = blockIdx.x;
  if (bid < 512) {
    int b = bid >> 6;
    const float* phi = Y + (long)bid * 1536;
    ph[threadIdx.x] = phi[threadIdx.x];
    ph[threadIdx.x + 256] = phi[threadIdx.x + 256];
    __syncthreads();
    int j = threadIdx.x >> 2, q = threadIdx.x & 3;
    const float* psi = Y + (long)(b*64 + j) * 1536 + 512;
    float s = 0.f;
#pragma unroll 4
    for (int k = q*128; k < q*128 + 128; ++k) s += ph[k] * psi[k];
    s += __shfl_xor(s, 1);
    s += __shfl_xor(s, 2);
    if (q == 0) out[(long)bid*64 + j] = 1.f / (1.f + expf(-s));
  } else {
    int r = bid - 512;
    int b = r >> 7;
    int i0 = pairs[r*2], i1 = pairs[r*2+1];
    const float* n0 = Y + (long)(b*64 + i0)*1536 + 1024;
    const float* n1 = Y + (long)(b*64 + i1)*1536 + 1024;
    float* o = out + 32768 + (long)r*1024;
    for (int c = threadIdx.x; c < 512; c += 256)
      o[c] = 0.5f*(n0[c] + n1[c]);
  }
}

extern "C" void kernel_launch(void* const* d_in, const int* in_sizes, int n_in,
                              void* d_out, int out_size, void* d_ws, size_t ws_size,
                              hipStream_t stream) {
  const float* x     = (const float*)d_in[0];
  const float* feat  = (const float*)d_in[1];
  const float* Wphi  = (const float*)d_in[2];
  const float* bphi  = (const float*)d_in[3];
  const float* Wpsi  = (const float*)d_in[4];
  const float* bpsi  = (const float*)d_in[5];
  const float* Wnode = (const float*)d_in[6];
  const float* bnode = (const float*)d_in[7];
  const float* Wrel  = (const float*)d_in[8];
  const float* brel  = (const float*)d_in[9];
  const int*   pairs = (const int*)d_in[10];
  float* out = (float*)d_out;
  char* ws = (char*)d_ws;

  h16*   xh    = (h16*)(ws + 0);
  h16*   W3t   = (h16*)(ws + 2097152);
  h16*   Wrelt = (h16*)(ws + 8388608);
  h16*   G     = (h16*)(ws + 9437184);
  float* b3    = (float*)(ws + 11534336);
  float* Y     = (float*)(ws + 11540480);

  k_prep<<<dim3(5126), dim3(256), 0, stream>>>(
      Wphi, Wpsi, Wnode, Wrel, x, bphi, bpsi, bnode, feat, pairs,
      W3t, Wrelt, xh, b3, G);
  k_gemm<<<dim3(320), dim3(256), 0, stream>>>(
      xh, W3t, b3, Y,
      G, Wrelt, brel, out + 32768 + 512);
  k_epilogue<<<dim3(1536), dim3(256), 0, stream>>>(Y, pairs, out);
}

// Round 3
// 41.911 us; speedup vs baseline: 1.9958x; 1.2449x over previous
//
#include <hip/hip_runtime.h>
#include <hip/hip_bf16.h>

// B=8, N=64, P=128, DNODE=2048, DEDGE=1024, DEMB=512, E=32768
// edge_locating_tensor is the canonical meshgrid -> lookup(b,i,j) = b*4096+i*64+j.
// Only 2*B*P=2048 of 32768 edge rows are used; (e1+e2)*0.5 folds into the GEMM
// input (linearity) -> edge GEMM is 1024x512x1024.
// Scores computed as per-batch MFMA GEMM phi_h @ psi_h^T from an f16 copy of Y.

typedef _Float16 h16;
typedef h16 h16x4 __attribute__((ext_vector_type(4)));
typedef h16 h16x8 __attribute__((ext_vector_type(8)));
typedef float f32x4 __attribute__((ext_vector_type(4)));

// ---------------- ws layout (bytes) ----------------
// xh    : 0         512*2048*2  = 2097152
// W3t   : 2097152   1536*2048*2 = 6291456   (phi|psi|node, K-major)
// Wrelt : 8388608   512*1024*2  = 1048576
// G     : 9437184   1024*1024*2 = 2097152   (0.5*(f_fwd+f_rev), f16)
// b3    : 11534336  1536*4      = 6144
// Y     : 11540480  512*1536*4  = 3145728   (phi|psi|node_emb fp32)
// Yh    : 14686208  512*1024*2  = 1048576   (phi|psi f16, row stride 1024)

__global__ __launch_bounds__(256) void k_prep(
    const float* __restrict__ Wphi, const float* __restrict__ Wpsi,
    const float* __restrict__ Wnode, const float* __restrict__ Wrel,
    const float* __restrict__ x, const float* __restrict__ bphi,
    const float* __restrict__ bpsi, const float* __restrict__ bnode,
    const float* __restrict__ feat, const int* __restrict__ pairs,
    h16* __restrict__ W3t, h16* __restrict__ Wrelt, h16* __restrict__ xh,
    float* __restrict__ b3, h16* __restrict__ G) {
  __shared__ float t[32][33];
  int bid = blockIdx.x;
  if (bid < 3584) {
    const float* src; h16* dst; int K, tk, tn;
    if (bid < 3072) {
      int mat = bid >> 10, rem = bid & 1023;
      tk = rem >> 4; tn = rem & 15;
      src = mat == 0 ? Wphi : (mat == 1 ? Wpsi : Wnode);
      K = 2048; dst = W3t + (long)mat * 512 * 2048;
    } else {
      int rem = bid - 3072;
      tk = rem >> 4; tn = rem & 15;
      src = Wrel; K = 1024; dst = Wrelt;
    }
    int tx = threadIdx.x & 31, ty = threadIdx.x >> 5;
#pragma unroll
    for (int it = 0; it < 4; ++it)
      t[ty + it*8][tx] = src[(long)(tk*32 + ty + it*8)*512 + tn*32 + tx];
    __syncthreads();
#pragma unroll
    for (int it = 0; it < 4; ++it)
      dst[(long)(tn*32 + ty + it*8)*K + tk*32 + tx] = (h16)t[tx][ty + it*8];
  } else if (bid < 4102) {
    int b2 = bid - 3584;
    if (b2 < 512) {
      int idx = (b2*256 + threadIdx.x) * 8;
      const float4* xv = (const float4*)(x + idx);
      float4 v0 = xv[0], v1 = xv[1];
      h16x8 o;
      o[0]=(h16)v0.x; o[1]=(h16)v0.y; o[2]=(h16)v0.z; o[3]=(h16)v0.w;
      o[4]=(h16)v1.x; o[5]=(h16)v1.y; o[6]=(h16)v1.z; o[7]=(h16)v1.w;
      *(h16x8*)(xh + idx) = o;
    } else {
      int i = (b2 - 512)*256 + threadIdx.x;
      if (i < 1536) b3[i] = i < 512 ? bphi[i] : (i < 1024 ? bpsi[i-512] : bnode[i-1024]);
    }
  } else {
    int r = bid - 4102;            // r = b*128 + p
    int b = r >> 7;
    int i0 = pairs[r*2], i1 = pairs[r*2+1];
    const float4* f0 = (const float4*)(feat + (long)((b*64 + i0)*64 + i1) * 1024);
    const float4* f1 = (const float4*)(feat + (long)((b*64 + i1)*64 + i0) * 1024);
    int k = threadIdx.x;
    float4 a = f0[k], c = f1[k];
    h16x4 o;
    o[0]=(h16)(0.5f*(a.x+c.x)); o[1]=(h16)(0.5f*(a.y+c.y));
    o[2]=(h16)(0.5f*(a.z+c.z)); o[3]=(h16)(0.5f*(a.w+c.w));
    *(h16x4*)(G + (long)r*1024 + k*4) = o;
  }
}

// 2 kc x 4 MFMA on one staged 64x64 K-chunk.
__device__ __forceinline__ void mfma_compute(
    const h16 (*__restrict__ As)[72], const h16 (*__restrict__ Bs)[72],
    int wm, int wn, int fr, int kg, f32x4 acc[2][2]) {
#pragma unroll
  for (int kc = 0; kc < 2; ++kc) {
    int kb = kc*32 + kg;
    h16x8 fa0 = *(const h16x8*)&As[wm*32 + fr][kb];
    h16x8 fa1 = *(const h16x8*)&As[wm*32 + 16 + fr][kb];
    h16x8 fb0 = *(const h16x8*)&Bs[wn*32 + fr][kb];
    h16x8 fb1 = *(const h16x8*)&Bs[wn*32 + 16 + fr][kb];
    acc[0][0] = __builtin_amdgcn_mfma_f32_16x16x32_f16(fa0, fb0, acc[0][0], 0,0,0);
    acc[0][1] = __builtin_amdgcn_mfma_f32_16x16x32_f16(fa0, fb1, acc[0][1], 0,0,0);
    acc[1][0] = __builtin_amdgcn_mfma_f32_16x16x32_f16(fa1, fb0, acc[1][0], 0,0,0);
    acc[1][1] = __builtin_amdgcn_mfma_f32_16x16x32_f16(fa1, fb1, acc[1][1], 0,0,0);
  }
}

// Double-buffered reg-staged pipeline: issue loads for t+1, compute t, write
// t+1 to the other buffer, ONE barrier per step.
#define GEMM_PIPELINE(Agp, Bgp, K)                                        \
  {                                                                       \
    h16x8 ra0 = *(const h16x8*)(Agp);                                     \
    h16x8 ra1 = *(const h16x8*)(Agp + 8);                                 \
    h16x8 rb0 = *(const h16x8*)(Bgp);                                     \
    h16x8 rb1 = *(const h16x8*)(Bgp + 8);                                 \
    *(h16x8*)&As[0][srow][skp]   = ra0;                                   \
    *(h16x8*)&As[0][srow][skp+8] = ra1;                                   \
    *(h16x8*)&Bs[0][srow][skp]   = rb0;                                   \
    *(h16x8*)&Bs[0][srow][skp+8] = rb1;                                   \
    __syncthreads();                                                      \
    int cur = 0;                                                          \
    for (int k0 = 64; k0 < (K); k0 += 64) {                               \
      ra0 = *(const h16x8*)(Agp + k0);                                    \
      ra1 = *(const h16x8*)(Agp + k0 + 8);                                \
      rb0 = *(const h16x8*)(Bgp + k0);                                    \
      rb1 = *(const h16x8*)(Bgp + k0 + 8);                                \
      mfma_compute(As[cur], Bs[cur], wm, wn, fr, kg, acc);                \
      int nxt = cur ^ 1;                                                  \
      *(h16x8*)&As[nxt][srow][skp]   = ra0;                               \
      *(h16x8*)&As[nxt][srow][skp+8] = ra1;                               \
      *(h16x8*)&Bs[nxt][srow][skp]   = rb0;                               \
      *(h16x8*)&Bs[nxt][srow][skp+8] = rb1;                               \
      __syncthreads();                                                    \
      cur = nxt;                                                          \
    }                                                                     \
    mfma_compute(As[cur], Bs[cur], wm, wn, fr, kg, acc);                  \
  }

// Both GEMMs. blocks 0..191: Y(512x1536)=xh@W3t^T+b3 (also emits f16 phi|psi
// to Yh for cols<1024). blocks 192..319: out2(1024x512)=G@Wrelt^T+brel.
__global__ __launch_bounds__(256) void k_gemm(
    const h16* __restrict__ A1, const h16* __restrict__ B1,
    const float* __restrict__ bias1, float* __restrict__ C1,
    h16* __restrict__ Yh,
    const h16* __restrict__ A2, const h16* __restrict__ B2,
    const float* __restrict__ bias2, float* __restrict__ C2) {
  __shared__ __align__(16) h16 As[2][64][72];
  __shared__ __align__(16) h16 Bs[2][64][72];
  int bid = blockIdx.x;
  const h16 *A, *Bt; const float* bias; float* C;
  int K, ldc, tileM, tileN;
  if (bid < 192) {
    A = A1; Bt = B1; bias = bias1; C = C1; K = 2048; ldc = 1536;
    tileM = (bid / 24) * 64; tileN = (bid % 24) * 64;
  } else {
    int r = bid - 192;
    A = A2; Bt = B2; bias = bias2; C = C2; K = 1024; ldc = 1024;
    tileM = (r / 8) * 64; tileN = (r % 8) * 64;
  }
  int tid = threadIdx.x, lane = tid & 63, wave = tid >> 6;
  int wm = wave >> 1, wn = wave & 1;
  int srow = tid >> 2, skp = (tid & 3) * 16;
  int fr = lane & 15, kg = (lane >> 4) * 8;
  const h16* Agp = A + (long)(tileM + srow) * K + skp;
  const h16* Bgp = Bt + (long)(tileN + srow) * K + skp;
  f32x4 acc[2][2] = {};
  GEMM_PIPELINE(Agp, Bgp, K);
  int r0 = 4 * (lane >> 4), c0 = lane & 15;
  bool wantYh = (bid < 192) && (tileN < 1024);
#pragma unroll
  for (int m = 0; m < 2; ++m)
#pragma unroll
    for (int n = 0; n < 2; ++n) {
      int row = tileM + wm*32 + m*16 + r0;
      int col = tileN + wn*32 + n*16 + c0;
      float bb = bias[col];
#pragma unroll
      for (int r = 0; r < 4; ++r) {
        float v = acc[m][n][r] + bb;
        C[(long)(row + r) * ldc + col] = v;
        if (wantYh) Yh[(long)(row + r) * 1024 + col] = (h16)v;
      }
    }
}

// blocks 0..7: scores via MFMA, S_b = phi_h @ psi_h^T (64x64, K=512) + sigmoid.
// blocks 8..1031: classifier first half.
__global__ __launch_bounds__(256) void k_epilogue(
    const float* __restrict__ Y, const h16* __restrict__ Yh,
    const int* __restrict__ pairs, float* __restrict__ out) {
  __shared__ __align__(16) h16 As[2][64][72];
  __shared__ __align__(16) h16 Bs[2][64][72];
  int bid = blockIdx.x;
  if (bid < 8) {
    int tid = threadIdx.x, lane = tid & 63, wave = tid >> 6;
    int wm = wave >> 1, wn = wave & 1;
    int srow = tid >> 2, skp = (tid & 3) * 16;
    int fr = lane & 15, kg = (lane >> 4) * 8;
    const h16* Ab = Yh + (long)bid * 64 * 1024;
    const h16* Agp = Ab + (long)srow * 1024 + skp;         // phi rows
    const h16* Bgp = Ab + (long)srow * 1024 + 512 + skp;   // psi rows
    f32x4 acc[2][2] = {};
    GEMM_PIPELINE(Agp, Bgp, 512);
    int r0 = 4 * (lane >> 4), c0 = lane & 15;
    float* ob = out + (long)bid * 4096;
#pragma unroll
    for (int m = 0; m < 2; ++m)
#pragma unroll
      for (int n = 0; n < 2; ++n) {
        int row = wm*32 + m*16 + r0;
        int col = wn*32 + n*16 + c0;
#pragma unroll
        for (int r = 0; r < 4; ++r) {
          float s = acc[m][n][r];
          ob[(long)(row + r) * 64 + col] = 1.f / (1.f + expf(-s));
        }
      }
  } else {
    int r = bid - 8;
    int b = r >> 7;
    int i0 = pairs[r*2], i1 = pairs[r*2+1];
    const float* n0 = Y + (long)(b*64 + i0)*1536 + 1024;
    const float* n1 = Y + (long)(b*64 + i1)*1536 + 1024;
    float* o = out + 32768 + (long)r*1024;
    for (int c = threadIdx.x; c < 512; c += 256)
      o[c] = 0.5f*(n0[c] + n1[c]);
  }
}

extern "C" void kernel_launch(void* const* d_in, const int* in_sizes, int n_in,
                              void* d_out, int out_size, void* d_ws, size_t ws_size,
                              hipStream_t stream) {
  const float* x     = (const float*)d_in[0];
  const float* feat  = (const float*)d_in[1];
  const float* Wphi  = (const float*)d_in[2];
  const float* bphi  = (const float*)d_in[3];
  const float* Wpsi  = (const float*)d_in[4];
  const float* bpsi  = (const float*)d_in[5];
  const float* Wnode = (const float*)d_in[6];
  const float* bnode = (const float*)d_in[7];
  const float* Wrel  = (const float*)d_in[8];
  const float* brel  = (const float*)d_in[9];
  const int*   pairs = (const int*)d_in[10];
  float* out = (float*)d_out;
  char* ws = (char*)d_ws;

  h16*   xh    = (h16*)(ws + 0);
  h16*   W3t   = (h16*)(ws + 2097152);
  h16*   Wrelt = (h16*)(ws + 8388608);
  h16*   G     = (h16*)(ws + 9437184);
  float* b3    = (float*)(ws + 11534336);
  float* Y     = (float*)(ws + 11540480);
  h16*   Yh    = (h16*)(ws + 14686208);

  k_prep<<<dim3(5126), dim3(256), 0, stream>>>(
      Wphi, Wpsi, Wnode, Wrel, x, bphi, bpsi, bnode, feat, pairs,
      W3t, Wrelt, xh, b3, G);
  k_gemm<<<dim3(320), dim3(256), 0, stream>>>(
      xh, W3t, b3, Y, Yh,
      G, Wrelt, brel, out + 32768 + 512);
  k_epilogue<<<dim3(1032), dim3(256), 0, stream>>>(Y, Yh, pairs, out);
}